// Round 4
// baseline (1620.715 us; speedup 1.0000x reference)
//
#include <hip/hip_runtime.h>
#include <stdint.h>

// ============================ problem constants ============================
constexpr int VOC  = 50257;
constexpr int VPAD = 50304;          // VOC padded up to a multiple of 128
constexpr int DEMB = 768;
constexpr int NQ   = 4096;           // B*T
constexpr float EPS_HALF = 0.05f;    // EPSILON / 2
constexpr float LOG2E = 1.4426950408889634f;
constexpr float C16   = -23.083120654223414f;   // -16 * log2(e); fixed softmax "max"
// logit = sim*0.05 + gumbel < 16 always (gumbel <= -ln 2^-23 = 15.94, |sim*0.05| <= .05)
// P = exp(logit - 16) = exp2(simraw*rk2 + C16) / t,  t = -ln(u), rk2 = 0.05*log2e/||E_j||

typedef __attribute__((ext_vector_type(4))) short    short4_t;
typedef __attribute__((ext_vector_type(8))) short    short8_t;
typedef __attribute__((ext_vector_type(4))) float    float4_t;
typedef __attribute__((ext_vector_type(4))) uint32_t uint4_t;

// ============================ small helpers ================================
__device__ __forceinline__ short f2bf(float f) {   // RNE float->bf16
  uint32_t u = __float_as_uint(f);
  u += 0x7FFFu + ((u >> 16) & 1u);
  return (short)(u >> 16);
}

// ---- 8 independent threefry2x32 hashes, key (0,42), counters e0..e0+7 ----
// bits = o0 ^ o1 (jax threefry_partitionable). Lockstep arrays -> 8-way ILP.
__device__ __forceinline__ void tf8(uint32_t e0, uint32_t out[8]) {
  const uint32_t K0 = 0u, K1 = 42u, K2 = 0x1BD11BDAu ^ 42u;
  uint32_t x0[8], x1[8];
#pragma unroll
  for (int r = 0; r < 8; ++r) { x0[r] = K0; x1[r] = e0 + (uint32_t)r + K1; }
#define R8(a) _Pragma("unroll") \
  for (int r = 0; r < 8; ++r) { x0[r] += x1[r]; x1[r] = __builtin_rotateleft32(x1[r], a) ^ x0[r]; }
#define INJ8(a, b, i) _Pragma("unroll") \
  for (int r = 0; r < 8; ++r) { x0[r] += (a); x1[r] += (b) + (uint32_t)(i); }
  R8(13) R8(15) R8(26) R8(6)
  INJ8(K1, K2, 1)
  R8(17) R8(29) R8(16) R8(24)
  INJ8(K2, K0, 2)
  R8(13) R8(15) R8(26) R8(6)
  INJ8(K0, K1, 3)
  R8(17) R8(29) R8(16) R8(24)
  INJ8(K1, K2, 4)
  R8(13) R8(15) R8(26) R8(6)
#pragma unroll
  for (int r = 0; r < 8; ++r) { x0[r] += K2; x1[r] += K0 + 5u; out[r] = x0[r] ^ x1[r]; }
#undef R8
#undef INJ8
}

// t = -ln(u), u = n*2^-23, n = bits>>9. Branchless: series near u->1 (dominant
// weights; fast-log cancellation), hw log2 otherwise. n==0 -> t=inf -> P=0 (negligible).
__device__ __forceinline__ float neg_ln_u(uint32_t bits) {
  uint32_t n = bits >> 9;
  uint32_t m = 8388608u - n;
  float t_log = (23.0f - __builtin_amdgcn_logf((float)n)) * 0.69314718055994531f;
  float x = (float)m * 1.1920928955078125e-7f;
  float t_ser = x * fmaf(x, fmaf(x, fmaf(x, 0.25f, 0.3333333333f), 0.5f), 1.0f);
  return (m < 32768u) ? t_ser : t_log;
}

// ============================ prep kernels =================================
// rk2[j] = (0.05/max(||E_j||,1e-12)) * log2e ; E -> bf16
__global__ void k_prep_e(const float* __restrict__ E, short* __restrict__ Eb,
                         float* __restrict__ rk2) {
  int j = blockIdx.x;            // 0..VPAD-1
  int t = threadIdx.x;
  __shared__ float red[4];
  float ssq = 0.f;
  if (j < VOC) {
    if (t < 192) {
      float4_t v = *(const float4_t*)(E + (size_t)j * DEMB + t * 4);
      ssq = v[0]*v[0] + v[1]*v[1] + v[2]*v[2] + v[3]*v[3];
      short4_t b; b[0]=f2bf(v[0]); b[1]=f2bf(v[1]); b[2]=f2bf(v[2]); b[3]=f2bf(v[3]);
      *(short4_t*)(Eb + (size_t)j * DEMB + t * 4) = b;
    }
  } else if (t < 192) {
    short4_t z = {0,0,0,0};
    *(short4_t*)(Eb + (size_t)j * DEMB + t * 4) = z;
  }
  for (int off = 32; off; off >>= 1) ssq += __shfl_xor(ssq, off);
  if ((t & 63) == 0) red[t >> 6] = ssq;
  __syncthreads();
  if (t == 0) {
    float s = red[0] + red[1] + red[2] + red[3];
    rk2[j] = (j < VOC) ? (EPS_HALF * LOG2E / fmaxf(sqrtf(s), 1e-12f)) : 0.f;
  }
}

__global__ void k_prep_q(const int* __restrict__ ids, const float* __restrict__ E,
                         short* __restrict__ qn) {
  int p = blockIdx.x;
  int t = threadIdx.x;
  int id = ids[p];
  __shared__ float red[4];
  __shared__ float scale_s;
  float4_t v = {0.f, 0.f, 0.f, 0.f};
  float ssq = 0.f;
  if (t < 192) {
    v = *(const float4_t*)(E + (size_t)id * DEMB + t * 4);
    ssq = v[0]*v[0] + v[1]*v[1] + v[2]*v[2] + v[3]*v[3];
  }
  for (int off = 32; off; off >>= 1) ssq += __shfl_xor(ssq, off);
  if ((t & 63) == 0) red[t >> 6] = ssq;
  __syncthreads();
  if (t == 0) scale_s = 1.0f / fmaxf(sqrtf(red[0]+red[1]+red[2]+red[3]), 1e-12f);
  __syncthreads();
  float sc = scale_s;
  if (t < 192) {
    short4_t b; b[0]=f2bf(v[0]*sc); b[1]=f2bf(v[1]*sc); b[2]=f2bf(v[2]*sc); b[3]=f2bf(v[3]*sc);
    *(short4_t*)(qn + (size_t)p * DEMB + t * 4) = b;
  }
}

// Et[d][key] = Eb[key][d]
__global__ void k_transpose(const short* __restrict__ Eb, short* __restrict__ Et) {
  int lane = threadIdx.x & 63;
  int dg   = threadIdx.x >> 6;
  int key  = blockIdx.x * 64 + lane;
  int d0   = blockIdx.y * 32 + dg * 8;
  short8_t v = *(const short8_t*)(Eb + (size_t)key * DEMB + d0);
#pragma unroll
  for (int q = 0; q < 8; ++q)
    Et[(size_t)(d0 + q) * VPAD + key] = v[q];
}

__global__ void k_zero(float* __restrict__ O, float* __restrict__ lsum) {
  int idx = blockIdx.x * 256 + threadIdx.x;      // float4 index over O
  if (idx < NQ) lsum[idx] = 0.f;
  float4_t z = {0.f, 0.f, 0.f, 0.f};
  ((float4_t*)O)[idx] = z;
}

// ============================ GEMM plumbing ================================
// 128x128 tile, BK=64, 256 threads (4 waves, 2x2 quadrants of 64x64),
// 16x16x32 bf16 MFMA. LDS holds the XOR-swizzled tile:
//   LDS[row*128B + (byte ^ ((row&7)<<4))] = g[row][byte]
// staged via global_load_lds (linear LDS dest = tid*16B, pre-swizzled SOURCE).
__device__ __forceinline__ int swz(int row, int byte) {
  return (row << 7) + (byte ^ ((row & 7) << 4));
}

__device__ __forceinline__ void stage_g2l(short* L, const short* __restrict__ g,
                                          long grow0, long stride, long col0, int tid) {
  int r7 = tid >> 3;
  int c8 = (tid & 7) << 3;                       // short offset, 16B units
#pragma unroll
  for (int i = 0; i < 4; ++i) {
    int  row = r7 + i * 32;
    long cs  = (long)(c8 ^ ((row & 7) << 3));    // pre-swizzled source col (shorts)
    const short* src = g + (grow0 + row) * stride + col0 + cs;
    short* dst = L + row * 64 + c8;              // linear: lane-monotone 16B/lane
    __builtin_amdgcn_global_load_lds(
        (const __attribute__((address_space(1))) void*)src,
        (__attribute__((address_space(3))) void*)dst, 16, 0, 0);
  }
}

// single ds_read_b128 fragment: reg r of k-group g holds k = ks*32 + 8g + r.
// A and B use the identical mapping, so the within-K permutation cancels in the dot.
__device__ __forceinline__ short8_t ldfrag(const short* L, int row, int kbyte) {
  return *(const short8_t*)(L + (swz(row, kbyte) >> 1));
}

// ---- GEMM1 (pure): S[p][jc] = qn_p . Eb_j   (raw sim, f16) ----
__global__ __launch_bounds__(256) void k_gemm1(
    const short* __restrict__ qn, const short* __restrict__ Eb,
    _Float16* __restrict__ S, int c0, int KC) {
  __shared__ short lA[128 * 64];
  __shared__ short lB[128 * 64];
  int tid = threadIdx.x, lane = tid & 63;
  int wv = tid >> 6, wr = wv >> 1, wc = wv & 1;
  int rowbase = blockIdx.x * 128;
  int colbase = blockIdx.y * 128;
  float4_t acc[4][4];
  float4_t zero = {0.f, 0.f, 0.f, 0.f};
#pragma unroll
  for (int mt = 0; mt < 4; ++mt)
#pragma unroll
    for (int nt = 0; nt < 4; ++nt) acc[mt][nt] = zero;

  for (int kt = 0; kt < DEMB / 64; ++kt) {
    __syncthreads();
    stage_g2l(lA, qn, rowbase,      DEMB, kt * 64, tid);
    stage_g2l(lB, Eb, c0 + colbase, DEMB, kt * 64, tid);
    __syncthreads();
#pragma unroll
    for (int ks = 0; ks < 2; ++ks) {
      int kb = ks * 64 + (lane >> 4) * 16;
      short8_t a[4], b[4];
#pragma unroll
      for (int mt = 0; mt < 4; ++mt) a[mt] = ldfrag(lA, wr * 64 + mt * 16 + (lane & 15), kb);
#pragma unroll
      for (int nt = 0; nt < 4; ++nt) b[nt] = ldfrag(lB, wc * 64 + nt * 16 + (lane & 15), kb);
#pragma unroll
      for (int mt = 0; mt < 4; ++mt)
#pragma unroll
        for (int nt = 0; nt < 4; ++nt)
          acc[mt][nt] = __builtin_amdgcn_mfma_f32_16x16x32_bf16(a[mt], b[nt], acc[mt][nt], 0, 0, 0);
    }
  }
  // epilogue: raw sims -> f16 (C/D layout: col = lane&15, row = (lane>>4)*4 + reg)
#pragma unroll
  for (int mt = 0; mt < 4; ++mt) {
    int prow = rowbase + wr * 64 + mt * 16 + ((lane >> 4) << 2);
    int jc0  = colbase + wc * 64 + (lane & 15);
#pragma unroll
    for (int r = 0; r < 4; ++r) {
      _Float16* dst = S + (size_t)(prow + r) * KC + jc0;
#pragma unroll
      for (int nt = 0; nt < 4; ++nt) dst[nt * 16] = (_Float16)acc[mt][nt][r];
    }
  }
}

// ---- gumbel/softmax pass: in-place f16 sim -> bf16 P, + row-sum atomics ----
// P = exp2(sim*rk2[j] + C16) * rcp(-ln u_j).  8 contiguous cols per thread.
__global__ __launch_bounds__(256) void k_gumbel(
    uint32_t* __restrict__ SP, const float* __restrict__ rk2,
    float* __restrict__ lsum, int c0, int KCeff, int KC) {
  int p    = blockIdx.x;
  int colq = blockIdx.y * 2048 + threadIdx.x * 8;
  float partial = 0.f;
  if (colq < KCeff) {
    uint32_t* base = SP + ((size_t)p * KC + colq) / 2;     // 2B elems -> u32 pairs
    uint4_t sv = *(const uint4_t*)base;                    // 8 f16 sims
    int j0 = c0 + colq;                                    // global vocab col
    // rk2 for 8 consecutive j
    float4_t rk_lo = *(const float4_t*)(rk2 + j0);
    float4_t rk_hi = *(const float4_t*)(rk2 + j0 + 4);
    uint32_t bits[8];
    tf8((uint32_t)p * (uint32_t)VOC + (uint32_t)j0, bits);
    float pe[8];
#pragma unroll
    for (int i = 0; i < 8; ++i) {
      uint32_t h = (sv[i >> 1] >> ((i & 1) * 16)) & 0xFFFFu;
      float sim = (float)__uint_as_float((h << 16) >> 16 | 0u) * 0.f; // placeholder avoided below
      (void)sim;
      _Float16 hf = *(_Float16*)&h;
      float simf = (float)hf;
      float rkj = (i < 4) ? rk_lo[i] : rk_hi[i - 4];
      float t = neg_ln_u(bits[i]);
      float v = __builtin_amdgcn_exp2f(fmaf(simf, rkj, C16)) * __builtin_amdgcn_rcpf(t);
      bool ok = (j0 + i) < VOC;
      pe[i] = ok ? v : 0.f;
      partial += pe[i];
    }
    // pack 8 bf16 via v_cvt_pk_bf16_f32 (RNE), store one dwordx4
    uint4_t pkv;
#pragma unroll
    for (int i = 0; i < 4; ++i) {
      uint32_t r;
      asm("v_cvt_pk_bf16_f32 %0, %1, %2" : "=v"(r) : "v"(pe[2 * i]), "v"(pe[2 * i + 1]));
      pkv[i] = r;
    }
    *(uint4_t*)base = pkv;
  }
  // wave reduce + one atomic per wave
  for (int off = 32; off; off >>= 1) partial += __shfl_xor(partial, off);
  if ((threadIdx.x & 63) == 0 && partial != 0.f) unsafeAtomicAdd(&lsum[p], partial);
}

// ---- GEMM2: O[p][d] += sum_k P[p][k] * Et[d][k]  (pure bf16 GEMM, split-K atomics) ----
__global__ __launch_bounds__(256) void k_gemm2(
    const short* __restrict__ P, const short* __restrict__ Et,
    float* __restrict__ O, int c0, int KC, int kseg) {
  __shared__ short lA[128 * 64];
  __shared__ short lB[128 * 64];
  int tid = threadIdx.x, lane = tid & 63;
  int wv = tid >> 6, wr = wv >> 1, wc = wv & 1;
  int rowbase = blockIdx.x * 128;
  int colbase = blockIdx.y * 128;                // output dim (<768)
  int kbase   = blockIdx.z * kseg;               // within chunk
  float4_t acc[4][4];
  float4_t zero = {0.f, 0.f, 0.f, 0.f};
#pragma unroll
  for (int mt = 0; mt < 4; ++mt)
#pragma unroll
    for (int nt = 0; nt < 4; ++nt) acc[mt][nt] = zero;

  for (int kt = 0; kt < kseg / 64; ++kt) {
    __syncthreads();
    stage_g2l(lA, P,  rowbase, KC,   kbase + kt * 64, tid);
    stage_g2l(lB, Et, colbase, VPAD, (long)c0 + kbase + kt * 64, tid);
    __syncthreads();
#pragma unroll
    for (int ks = 0; ks < 2; ++ks) {
      int kb = ks * 64 + (lane >> 4) * 16;
      short8_t a[4], b[4];
#pragma unroll
      for (int mt = 0; mt < 4; ++mt) a[mt] = ldfrag(lA, wr * 64 + mt * 16 + (lane & 15), kb);
#pragma unroll
      for (int nt = 0; nt < 4; ++nt) b[nt] = ldfrag(lB, wc * 64 + nt * 16 + (lane & 15), kb);
#pragma unroll
      for (int mt = 0; mt < 4; ++mt)
#pragma unroll
        for (int nt = 0; nt < 4; ++nt)
          acc[mt][nt] = __builtin_amdgcn_mfma_f32_16x16x32_bf16(a[mt], b[nt], acc[mt][nt], 0, 0, 0);
    }
  }
#pragma unroll
  for (int mt = 0; mt < 4; ++mt)
#pragma unroll
    for (int nt = 0; nt < 4; ++nt) {
      int d = colbase + wc * 64 + nt * 16 + (lane & 15);
#pragma unroll
      for (int r = 0; r < 4; ++r) {
        int p = rowbase + wr * 64 + mt * 16 + ((lane >> 4) << 2) + r;
        unsafeAtomicAdd(&O[(size_t)p * DEMB + d], acc[mt][nt][r]);
      }
    }
}

__global__ void k_finalize(const float* __restrict__ O, const float* __restrict__ lsum,
                           float* __restrict__ out) {
  int idx = blockIdx.x * 256 + threadIdx.x;      // float4 index
  float inv = 1.0f / lsum[idx / 192];            // 192 float4 per row
  float4_t v = ((const float4_t*)O)[idx];
  v[0]*=inv; v[1]*=inv; v[2]*=inv; v[3]*=inv;
  ((float4_t*)out)[idx] = v;
}

// ============================ host launcher ================================
extern "C" void kernel_launch(void* const* d_in, const int* in_sizes, int n_in,
                              void* d_out, int out_size, void* d_ws, size_t ws_size,
                              hipStream_t stream) {
  (void)in_sizes; (void)n_in; (void)out_size;
  const int*   ids = (const int*)d_in[0];
  const float* E   = (const float*)d_in[1];
  float*       out = (float*)d_out;

  char* w = (char*)d_ws;
  short* Eb = (short*)w;      w += (size_t)VPAD * DEMB * 2;   // 77.3 MB
  short* Et = (short*)w;      w += (size_t)DEMB * VPAD * 2;   // 77.3 MB
  short* qn = (short*)w;      w += (size_t)NQ * DEMB * 2;     // 6.3 MB
  float* O  = (float*)w;      w += (size_t)NQ * DEMB * 4;     // 12.6 MB
  float* rk2 = (float*)w;     w += (size_t)VPAD * 4;
  float* lsum = (float*)w;    w += NQ * 4;
  void*  SP = (void*)w;       // f16 sim chunk, overwritten in-place with bf16 P
  size_t fixed = (size_t)(w - (char*)d_ws);

  int KC = 2048;
  if      (fixed + (size_t)NQ * 8192 * 2 <= ws_size) KC = 8192;
  else if (fixed + (size_t)NQ * 4096 * 2 <= ws_size) KC = 4096;
  int chunks = (VPAD + KC - 1) / KC;

  k_zero<<<(NQ * DEMB / 4) / 256, 256, 0, stream>>>(O, lsum);
  k_prep_e<<<VPAD, 256, 0, stream>>>(E, Eb, rk2);
  k_prep_q<<<NQ, 256, 0, stream>>>(ids, E, qn);
  k_transpose<<<dim3(VPAD / 64, DEMB / 32), 256, 0, stream>>>(Eb, Et);

  for (int c = 0; c < chunks; ++c) {
    int c0 = c * KC;
    int KCeff = VPAD - c0; if (KCeff > KC) KCeff = KC;        // multiple of 128
    k_gemm1<<<dim3(NQ / 128, KCeff / 128), 256, 0, stream>>>(qn, Eb, (_Float16*)SP, c0, KC);
    k_gumbel<<<dim3(NQ, (KCeff + 2047) / 2048), 256, 0, stream>>>(
        (uint32_t*)SP, rk2, lsum, c0, KCeff, KC);
    int KS = 4;
    while (KS > 1 && (KCeff % (KS * 64)) != 0) KS >>= 1;
    k_gemm2<<<dim3(NQ / 128, DEMB / 128, KS), 256, 0, stream>>>(
        (const short*)SP, Et, O, c0, KC, KCeff / KS);
  }
  k_finalize<<<(NQ * DEMB / 4) / 256, 256, 0, stream>>>(O, lsum, out);
}

// Round 5
// 1562.056 us; speedup vs baseline: 1.0376x; 1.0376x over previous
//
#include <hip/hip_runtime.h>
#include <stdint.h>

// ============================ problem constants ============================
constexpr int VOC  = 50257;
constexpr int VPAD = 50304;          // VOC padded up to a multiple of 128
constexpr int DEMB = 768;
constexpr int NQ   = 4096;           // B*T
constexpr float EPS_HALF = 0.05f;    // EPSILON / 2
constexpr float LOG2E = 1.4426950408889634f;
constexpr float C16   = -23.083120654223414f;   // -16 * log2(e); fixed softmax "max"
// logit = sim*0.05 + gumbel < 16 always (gumbel <= -ln 2^-23 = 15.94, |sim*0.05| <= .05)
// P = exp(logit - 16) = exp2(simraw*rk2 + C16) / t,  t = -ln(u), rk2 = 0.05*log2e/||E_j||

typedef __attribute__((ext_vector_type(4))) short    short4_t;
typedef __attribute__((ext_vector_type(8))) short    short8_t;
typedef __attribute__((ext_vector_type(4))) float    float4_t;
typedef __attribute__((ext_vector_type(4))) uint32_t uint4_t;

// ============================ small helpers ================================
__device__ __forceinline__ short f2bf(float f) {   // RNE float->bf16
  uint32_t u = __float_as_uint(f);
  u += 0x7FFFu + ((u >> 16) & 1u);
  return (short)(u >> 16);
}

// ---- 8 independent threefry2x32 hashes, key (0,42), counters e0..e0+7 ----
// bits = o0 ^ o1 (jax threefry_partitionable). Lockstep arrays -> 8-way ILP.
__device__ __forceinline__ void tf8(uint32_t e0, uint32_t out[8]) {
  const uint32_t K0 = 0u, K1 = 42u, K2 = 0x1BD11BDAu ^ 42u;
  uint32_t x0[8], x1[8];
#pragma unroll
  for (int r = 0; r < 8; ++r) { x0[r] = K0; x1[r] = e0 + (uint32_t)r + K1; }
#define R8(a) _Pragma("unroll") \
  for (int r = 0; r < 8; ++r) { x0[r] += x1[r]; x1[r] = __builtin_rotateleft32(x1[r], a) ^ x0[r]; }
#define INJ8(a, b, i) _Pragma("unroll") \
  for (int r = 0; r < 8; ++r) { x0[r] += (a); x1[r] += (b) + (uint32_t)(i); }
  R8(13) R8(15) R8(26) R8(6)
  INJ8(K1, K2, 1)
  R8(17) R8(29) R8(16) R8(24)
  INJ8(K2, K0, 2)
  R8(13) R8(15) R8(26) R8(6)
  INJ8(K0, K1, 3)
  R8(17) R8(29) R8(16) R8(24)
  INJ8(K1, K2, 4)
  R8(13) R8(15) R8(26) R8(6)
#pragma unroll
  for (int r = 0; r < 8; ++r) { x0[r] += K2; x1[r] += K0 + 5u; out[r] = x0[r] ^ x1[r]; }
#undef R8
#undef INJ8
}

// t = -ln(u), u = n*2^-23, n = bits>>9. Branchless: series near u->1 (dominant
// weights; fast-log cancellation), hw log2 otherwise. n==0 -> t=inf -> P=0 (negligible).
__device__ __forceinline__ float neg_ln_u(uint32_t bits) {
  uint32_t n = bits >> 9;
  uint32_t m = 8388608u - n;
  float t_log = (23.0f - __builtin_amdgcn_logf((float)n)) * 0.69314718055994531f;
  float x = (float)m * 1.1920928955078125e-7f;
  float t_ser = x * fmaf(x, fmaf(x, fmaf(x, 0.25f, 0.3333333333f), 0.5f), 1.0f);
  return (m < 32768u) ? t_ser : t_log;
}

// ============================ prep kernels =================================
// rk2[j] = (0.05/max(||E_j||,1e-12)) * log2e ; E -> bf16
__global__ void k_prep_e(const float* __restrict__ E, short* __restrict__ Eb,
                         float* __restrict__ rk2) {
  int j = blockIdx.x;            // 0..VPAD-1
  int t = threadIdx.x;
  __shared__ float red[4];
  float ssq = 0.f;
  if (j < VOC) {
    if (t < 192) {
      float4_t v = *(const float4_t*)(E + (size_t)j * DEMB + t * 4);
      ssq = v[0]*v[0] + v[1]*v[1] + v[2]*v[2] + v[3]*v[3];
      short4_t b; b[0]=f2bf(v[0]); b[1]=f2bf(v[1]); b[2]=f2bf(v[2]); b[3]=f2bf(v[3]);
      *(short4_t*)(Eb + (size_t)j * DEMB + t * 4) = b;
    }
  } else if (t < 192) {
    short4_t z = {0,0,0,0};
    *(short4_t*)(Eb + (size_t)j * DEMB + t * 4) = z;
  }
  for (int off = 32; off; off >>= 1) ssq += __shfl_xor(ssq, off);
  if ((t & 63) == 0) red[t >> 6] = ssq;
  __syncthreads();
  if (t == 0) {
    float s = red[0] + red[1] + red[2] + red[3];
    rk2[j] = (j < VOC) ? (EPS_HALF * LOG2E / fmaxf(sqrtf(s), 1e-12f)) : 0.f;
  }
}

__global__ void k_prep_q(const int* __restrict__ ids, const float* __restrict__ E,
                         short* __restrict__ qn) {
  int p = blockIdx.x;
  int t = threadIdx.x;
  int id = ids[p];
  __shared__ float red[4];
  __shared__ float scale_s;
  float4_t v = {0.f, 0.f, 0.f, 0.f};
  float ssq = 0.f;
  if (t < 192) {
    v = *(const float4_t*)(E + (size_t)id * DEMB + t * 4);
    ssq = v[0]*v[0] + v[1]*v[1] + v[2]*v[2] + v[3]*v[3];
  }
  for (int off = 32; off; off >>= 1) ssq += __shfl_xor(ssq, off);
  if ((t & 63) == 0) red[t >> 6] = ssq;
  __syncthreads();
  if (t == 0) scale_s = 1.0f / fmaxf(sqrtf(red[0]+red[1]+red[2]+red[3]), 1e-12f);
  __syncthreads();
  float sc = scale_s;
  if (t < 192) {
    short4_t b; b[0]=f2bf(v[0]*sc); b[1]=f2bf(v[1]*sc); b[2]=f2bf(v[2]*sc); b[3]=f2bf(v[3]*sc);
    *(short4_t*)(qn + (size_t)p * DEMB + t * 4) = b;
  }
}

// Et[d][key] = Eb[key][d]
__global__ void k_transpose(const short* __restrict__ Eb, short* __restrict__ Et) {
  int lane = threadIdx.x & 63;
  int dg   = threadIdx.x >> 6;
  int key  = blockIdx.x * 64 + lane;
  int d0   = blockIdx.y * 32 + dg * 8;
  short8_t v = *(const short8_t*)(Eb + (size_t)key * DEMB + d0);
#pragma unroll
  for (int q = 0; q < 8; ++q)
    Et[(size_t)(d0 + q) * VPAD + key] = v[q];
}

__global__ void k_zero(float* __restrict__ O, float* __restrict__ lsum) {
  int idx = blockIdx.x * 256 + threadIdx.x;      // float4 index over O
  if (idx < NQ) lsum[idx] = 0.f;
  float4_t z = {0.f, 0.f, 0.f, 0.f};
  ((float4_t*)O)[idx] = z;
}

// ============================ GEMM plumbing ================================
// 128x128 tile, BK=64, 256 threads (4 waves, 2x2 quadrants of 64x64),
// 16x16x32 bf16 MFMA. LDS holds the XOR-swizzled tile:
//   LDS[row*128B + (byte ^ ((row&7)<<4))] = g[row][byte]
// staged via global_load_lds (linear LDS dest = tid*16B, pre-swizzled SOURCE).
__device__ __forceinline__ int swz(int row, int byte) {
  return (row << 7) + (byte ^ ((row & 7) << 4));
}

__device__ __forceinline__ void stage_g2l(short* L, const short* __restrict__ g,
                                          long grow0, long stride, long col0, int tid) {
  int r7 = tid >> 3;
  int c8 = (tid & 7) << 3;                       // short offset, 16B units
#pragma unroll
  for (int i = 0; i < 4; ++i) {
    int  row = r7 + i * 32;
    long cs  = (long)(c8 ^ ((row & 7) << 3));    // pre-swizzled source col (shorts)
    const short* src = g + (grow0 + row) * stride + col0 + cs;
    short* dst = L + row * 64 + c8;              // linear: lane-monotone 16B/lane
    __builtin_amdgcn_global_load_lds(
        (const __attribute__((address_space(1))) void*)src,
        (__attribute__((address_space(3))) void*)dst, 16, 0, 0);
  }
}

// single ds_read_b128 fragment: reg r of k-group g holds k = ks*32 + 8g + r.
// A and B use the identical mapping, so the within-K permutation cancels in the dot.
__device__ __forceinline__ short8_t ldfrag(const short* L, int row, int kbyte) {
  return *(const short8_t*)(L + (swz(row, kbyte) >> 1));
}

// ---- GEMM1 (pure): S[p][jc] = qn_p . Eb_j   (raw sim, f16) ----
__global__ __launch_bounds__(256) void k_gemm1(
    const short* __restrict__ qn, const short* __restrict__ Eb,
    _Float16* __restrict__ S, int c0, int KC) {
  __shared__ short lA[128 * 64];
  __shared__ short lB[128 * 64];
  int tid = threadIdx.x, lane = tid & 63;
  int wv = tid >> 6, wr = wv >> 1, wc = wv & 1;
  int rowbase = blockIdx.x * 128;
  int colbase = blockIdx.y * 128;
  float4_t acc[4][4];
  float4_t zero = {0.f, 0.f, 0.f, 0.f};
#pragma unroll
  for (int mt = 0; mt < 4; ++mt)
#pragma unroll
    for (int nt = 0; nt < 4; ++nt) acc[mt][nt] = zero;

  for (int kt = 0; kt < DEMB / 64; ++kt) {
    __syncthreads();
    stage_g2l(lA, qn, rowbase,      DEMB, kt * 64, tid);
    stage_g2l(lB, Eb, c0 + colbase, DEMB, kt * 64, tid);
    __syncthreads();
#pragma unroll
    for (int ks = 0; ks < 2; ++ks) {
      int kb = ks * 64 + (lane >> 4) * 16;
      short8_t a[4], b[4];
#pragma unroll
      for (int mt = 0; mt < 4; ++mt) a[mt] = ldfrag(lA, wr * 64 + mt * 16 + (lane & 15), kb);
#pragma unroll
      for (int nt = 0; nt < 4; ++nt) b[nt] = ldfrag(lB, wc * 64 + nt * 16 + (lane & 15), kb);
#pragma unroll
      for (int mt = 0; mt < 4; ++mt)
#pragma unroll
        for (int nt = 0; nt < 4; ++nt)
          acc[mt][nt] = __builtin_amdgcn_mfma_f32_16x16x32_bf16(a[mt], b[nt], acc[mt][nt], 0, 0, 0);
    }
  }
  // epilogue: raw sims -> f16 (C/D layout: col = lane&15, row = (lane>>4)*4 + reg)
#pragma unroll
  for (int mt = 0; mt < 4; ++mt) {
    int prow = rowbase + wr * 64 + mt * 16 + ((lane >> 4) << 2);
    int jc0  = colbase + wc * 64 + (lane & 15);
#pragma unroll
    for (int r = 0; r < 4; ++r) {
      _Float16* dst = S + (size_t)(prow + r) * KC + jc0;
#pragma unroll
      for (int nt = 0; nt < 4; ++nt) dst[nt * 16] = (_Float16)acc[mt][nt][r];
    }
  }
}

// ---- gumbel/softmax pass: in-place f16 sim -> bf16 P, + row-sum atomics ----
// P = exp2(sim*rk2[j] + C16) * rcp(-ln u_j).  8 contiguous cols per thread.
__global__ __launch_bounds__(256) void k_gumbel(
    uint32_t* __restrict__ SP, const float* __restrict__ rk2,
    float* __restrict__ lsum, int c0, int KCeff, int KC) {
  int p    = blockIdx.x;
  int colq = blockIdx.y * 2048 + threadIdx.x * 8;
  float partial = 0.f;
  if (colq < KCeff) {
    uint32_t* base = SP + ((size_t)p * KC + colq) / 2;     // 2B elems -> u32 pairs
    uint4_t sv = *(const uint4_t*)base;                    // 8 f16 sims
    int j0 = c0 + colq;                                    // global vocab col
    float4_t rk_lo = *(const float4_t*)(rk2 + j0);
    float4_t rk_hi = *(const float4_t*)(rk2 + j0 + 4);
    uint32_t bits[8];
    tf8((uint32_t)p * (uint32_t)VOC + (uint32_t)j0, bits);
    float pe[8];
#pragma unroll
    for (int i = 0; i < 8; ++i) {
      uint32_t h = (sv[i >> 1] >> ((i & 1) * 16)) & 0xFFFFu;
      _Float16 hf = *(_Float16*)&h;
      float simf = (float)hf;
      float rkj = (i < 4) ? rk_lo[i] : rk_hi[i - 4];
      float t = neg_ln_u(bits[i]);
      float v = __builtin_amdgcn_exp2f(fmaf(simf, rkj, C16)) * __builtin_amdgcn_rcpf(t);
      bool ok = (j0 + i) < VOC;
      pe[i] = ok ? v : 0.f;
      partial += pe[i];
    }
    uint4_t pkv;
#pragma unroll
    for (int i = 0; i < 4; ++i) {
      uint32_t r;
      asm("v_cvt_pk_bf16_f32 %0, %1, %2" : "=v"(r) : "v"(pe[2 * i]), "v"(pe[2 * i + 1]));
      pkv[i] = r;
    }
    *(uint4_t*)base = pkv;
  }
  for (int off = 32; off; off >>= 1) partial += __shfl_xor(partial, off);
  if ((threadIdx.x & 63) == 0 && partial != 0.f) unsafeAtomicAdd(&lsum[p], partial);
}

// ---- GEMM2: O[p][d] += sum_k P[p][k] * Et[d][k] ----
// Double-buffered LDS, ONE __syncthreads per K-step: STAGE(t+1) issues before
// compute(t), so global_load_lds of the next tile flies under ds_read+MFMA of
// the current one; the top-of-iter barrier (vmcnt(0)+lgkmcnt(0)+s_barrier)
// drains loads that had a full compute phase to land. Race-free: stage and
// compute touch opposite buffers; overwrite-after-read ordered by the barrier.
__global__ __launch_bounds__(256) void k_gemm2(
    const short* __restrict__ P, const short* __restrict__ Et,
    float* __restrict__ O, int c0, int KC, int kseg) {
  __shared__ short lA[2][128 * 64];
  __shared__ short lB[2][128 * 64];
  int tid = threadIdx.x, lane = tid & 63;
  int wv = tid >> 6, wr = wv >> 1, wc = wv & 1;
  int rowbase = blockIdx.x * 128;
  int colbase = blockIdx.y * 128;                // output dim (<768)
  int kbase   = blockIdx.z * kseg;               // within chunk
  float4_t acc[4][4];
  float4_t zero = {0.f, 0.f, 0.f, 0.f};
#pragma unroll
  for (int mt = 0; mt < 4; ++mt)
#pragma unroll
    for (int nt = 0; nt < 4; ++nt) acc[mt][nt] = zero;

  int nt_steps = kseg / 64;
  stage_g2l(lA[0], P,  rowbase, KC,   kbase, tid);
  stage_g2l(lB[0], Et, colbase, VPAD, (long)c0 + kbase, tid);

  for (int kt = 0; kt < nt_steps; ++kt) {
    __syncthreads();                             // buf[cur] ready; aligns waves
    int cur = kt & 1;
    if (kt + 1 < nt_steps) {                     // issue next tile's loads now
      stage_g2l(lA[cur ^ 1], P,  rowbase, KC,   kbase + (kt + 1) * 64, tid);
      stage_g2l(lB[cur ^ 1], Et, colbase, VPAD, (long)c0 + kbase + (kt + 1) * 64, tid);
    }
#pragma unroll
    for (int ks = 0; ks < 2; ++ks) {
      int kb = ks * 64 + (lane >> 4) * 16;
      short8_t a[4], b[4];
#pragma unroll
      for (int mt = 0; mt < 4; ++mt) a[mt] = ldfrag(lA[cur], wr * 64 + mt * 16 + (lane & 15), kb);
#pragma unroll
      for (int nt = 0; nt < 4; ++nt) b[nt] = ldfrag(lB[cur], wc * 64 + nt * 16 + (lane & 15), kb);
#pragma unroll
      for (int mt = 0; mt < 4; ++mt)
#pragma unroll
        for (int nt = 0; nt < 4; ++nt)
          acc[mt][nt] = __builtin_amdgcn_mfma_f32_16x16x32_bf16(a[mt], b[nt], acc[mt][nt], 0, 0, 0);
    }
  }
#pragma unroll
  for (int mt = 0; mt < 4; ++mt)
#pragma unroll
    for (int nt = 0; nt < 4; ++nt) {
      int d = colbase + wc * 64 + nt * 16 + (lane & 15);
#pragma unroll
      for (int r = 0; r < 4; ++r) {
        int p = rowbase + wr * 64 + mt * 16 + ((lane >> 4) << 2) + r;
        unsafeAtomicAdd(&O[(size_t)p * DEMB + d], acc[mt][nt][r]);
      }
    }
}

__global__ void k_finalize(const float* __restrict__ O, const float* __restrict__ lsum,
                           float* __restrict__ out) {
  int idx = blockIdx.x * 256 + threadIdx.x;      // float4 index
  float inv = 1.0f / lsum[idx / 192];            // 192 float4 per row
  float4_t v = ((const float4_t*)O)[idx];
  v[0]*=inv; v[1]*=inv; v[2]*=inv; v[3]*=inv;
  ((float4_t*)out)[idx] = v;
}

// ============================ host launcher ================================
extern "C" void kernel_launch(void* const* d_in, const int* in_sizes, int n_in,
                              void* d_out, int out_size, void* d_ws, size_t ws_size,
                              hipStream_t stream) {
  (void)in_sizes; (void)n_in; (void)out_size;
  const int*   ids = (const int*)d_in[0];
  const float* E   = (const float*)d_in[1];
  float*       out = (float*)d_out;

  char* w = (char*)d_ws;
  short* Eb = (short*)w;      w += (size_t)VPAD * DEMB * 2;   // 77.3 MB
  short* Et = (short*)w;      w += (size_t)DEMB * VPAD * 2;   // 77.3 MB
  short* qn = (short*)w;      w += (size_t)NQ * DEMB * 2;     // 6.3 MB
  float* O  = (float*)w;      w += (size_t)NQ * DEMB * 4;     // 12.6 MB
  float* rk2 = (float*)w;     w += (size_t)VPAD * 4;
  float* lsum = (float*)w;    w += NQ * 4;
  void*  SP = (void*)w;       // f16 sim chunk, overwritten in-place with bf16 P
  size_t fixed = (size_t)(w - (char*)d_ws);

  int KC = 2048;
  if      (fixed + (size_t)NQ * 8192 * 2 <= ws_size) KC = 8192;
  else if (fixed + (size_t)NQ * 4096 * 2 <= ws_size) KC = 4096;
  int chunks = (VPAD + KC - 1) / KC;

  k_zero<<<(NQ * DEMB / 4) / 256, 256, 0, stream>>>(O, lsum);
  k_prep_e<<<VPAD, 256, 0, stream>>>(E, Eb, rk2);
  k_prep_q<<<NQ, 256, 0, stream>>>(ids, E, qn);
  k_transpose<<<dim3(VPAD / 64, DEMB / 32), 256, 0, stream>>>(Eb, Et);

  for (int c = 0; c < chunks; ++c) {
    int c0 = c * KC;
    int KCeff = VPAD - c0; if (KCeff > KC) KCeff = KC;        // multiple of 128
    k_gemm1<<<dim3(NQ / 128, KCeff / 128), 256, 0, stream>>>(qn, Eb, (_Float16*)SP, c0, KC);
    k_gumbel<<<dim3(NQ, (KCeff + 2047) / 2048), 256, 0, stream>>>(
        (uint32_t*)SP, rk2, lsum, c0, KCeff, KC);
    int KS = 4;
    while (KS > 1 && (KCeff % (KS * 64)) != 0) KS >>= 1;
    k_gemm2<<<dim3(NQ / 128, DEMB / 128, KS), 256, 0, stream>>>(
        (const short*)SP, Et, O, c0, KC, KCeff / KS);
  }
  k_finalize<<<(NQ * DEMB / 4) / 256, 256, 0, stream>>>(O, lsum, out);
}

// Round 6
// 1549.802 us; speedup vs baseline: 1.0458x; 1.0079x over previous
//
#include <hip/hip_runtime.h>
#include <stdint.h>

// ============================ problem constants ============================
constexpr int VOC  = 50257;
constexpr int VPAD = 50304;          // VOC padded up to a multiple of 128
constexpr int DEMB = 768;
constexpr int NQ   = 4096;           // B*T
constexpr float EPS_HALF = 0.05f;    // EPSILON / 2
constexpr float LOG2E = 1.4426950408889634f;
constexpr float C16   = -23.083120654223414f;   // -16 * log2(e); fixed softmax "max"
// logit = sim*0.05 + gumbel < 16 always (gumbel <= -ln 2^-23 = 15.94, |sim*0.05| <= .05)
// P = exp(logit - 16) = exp2(simraw*rk2 + C16) / t,  t = -ln(u), rk2 = 0.05*log2e/||E_j||

typedef __attribute__((ext_vector_type(4))) short    short4_t;
typedef __attribute__((ext_vector_type(8))) short    short8_t;
typedef __attribute__((ext_vector_type(4))) float    float4_t;
typedef __attribute__((ext_vector_type(4))) uint32_t uint4_t;

#define VMW(N) asm volatile("s_waitcnt vmcnt(" #N ")" ::: "memory")

// ============================ small helpers ================================
__device__ __forceinline__ short f2bf(float f) {   // RNE float->bf16
  uint32_t u = __float_as_uint(f);
  u += 0x7FFFu + ((u >> 16) & 1u);
  return (short)(u >> 16);
}

// ---- 8 independent threefry2x32 hashes, key (0,42), counters e0..e0+7 ----
// bits = o0 ^ o1 (jax threefry_partitionable). Lockstep arrays -> 8-way ILP.
__device__ __forceinline__ void tf8(uint32_t e0, uint32_t out[8]) {
  const uint32_t K0 = 0u, K1 = 42u, K2 = 0x1BD11BDAu ^ 42u;
  uint32_t x0[8], x1[8];
#pragma unroll
  for (int r = 0; r < 8; ++r) { x0[r] = K0; x1[r] = e0 + (uint32_t)r + K1; }
#define R8(a) _Pragma("unroll") \
  for (int r = 0; r < 8; ++r) { x0[r] += x1[r]; x1[r] = __builtin_rotateleft32(x1[r], a) ^ x0[r]; }
#define INJ8(a, b, i) _Pragma("unroll") \
  for (int r = 0; r < 8; ++r) { x0[r] += (a); x1[r] += (b) + (uint32_t)(i); }
  R8(13) R8(15) R8(26) R8(6)
  INJ8(K1, K2, 1)
  R8(17) R8(29) R8(16) R8(24)
  INJ8(K2, K0, 2)
  R8(13) R8(15) R8(26) R8(6)
  INJ8(K0, K1, 3)
  R8(17) R8(29) R8(16) R8(24)
  INJ8(K1, K2, 4)
  R8(13) R8(15) R8(26) R8(6)
#pragma unroll
  for (int r = 0; r < 8; ++r) { x0[r] += K2; x1[r] += K0 + 5u; out[r] = x0[r] ^ x1[r]; }
#undef R8
#undef INJ8
}

// t = -ln(u), u = n*2^-23, n = bits>>9. Branchless: series near u->1 (dominant
// weights; fast-log cancellation), hw log2 otherwise. n==0 -> t=inf -> P=0 (negligible).
__device__ __forceinline__ float neg_ln_u(uint32_t bits) {
  uint32_t n = bits >> 9;
  uint32_t m = 8388608u - n;
  float t_log = (23.0f - __builtin_amdgcn_logf((float)n)) * 0.69314718055994531f;
  float x = (float)m * 1.1920928955078125e-7f;
  float t_ser = x * fmaf(x, fmaf(x, fmaf(x, 0.25f, 0.3333333333f), 0.5f), 1.0f);
  return (m < 32768u) ? t_ser : t_log;
}

// ============================ prep kernels =================================
// rk2[j] = (0.05/max(||E_j||,1e-12)) * log2e ; E -> bf16
__global__ void k_prep_e(const float* __restrict__ E, short* __restrict__ Eb,
                         float* __restrict__ rk2) {
  int j = blockIdx.x;            // 0..VPAD-1
  int t = threadIdx.x;
  __shared__ float red[4];
  float ssq = 0.f;
  if (j < VOC) {
    if (t < 192) {
      float4_t v = *(const float4_t*)(E + (size_t)j * DEMB + t * 4);
      ssq = v[0]*v[0] + v[1]*v[1] + v[2]*v[2] + v[3]*v[3];
      short4_t b; b[0]=f2bf(v[0]); b[1]=f2bf(v[1]); b[2]=f2bf(v[2]); b[3]=f2bf(v[3]);
      *(short4_t*)(Eb + (size_t)j * DEMB + t * 4) = b;
    }
  } else if (t < 192) {
    short4_t z = {0,0,0,0};
    *(short4_t*)(Eb + (size_t)j * DEMB + t * 4) = z;
  }
  for (int off = 32; off; off >>= 1) ssq += __shfl_xor(ssq, off);
  if ((t & 63) == 0) red[t >> 6] = ssq;
  __syncthreads();
  if (t == 0) {
    float s = red[0] + red[1] + red[2] + red[3];
    rk2[j] = (j < VOC) ? (EPS_HALF * LOG2E / fmaxf(sqrtf(s), 1e-12f)) : 0.f;
  }
}

__global__ void k_prep_q(const int* __restrict__ ids, const float* __restrict__ E,
                         short* __restrict__ qn) {
  int p = blockIdx.x;
  int t = threadIdx.x;
  int id = ids[p];
  __shared__ float red[4];
  __shared__ float scale_s;
  float4_t v = {0.f, 0.f, 0.f, 0.f};
  float ssq = 0.f;
  if (t < 192) {
    v = *(const float4_t*)(E + (size_t)id * DEMB + t * 4);
    ssq = v[0]*v[0] + v[1]*v[1] + v[2]*v[2] + v[3]*v[3];
  }
  for (int off = 32; off; off >>= 1) ssq += __shfl_xor(ssq, off);
  if ((t & 63) == 0) red[t >> 6] = ssq;
  __syncthreads();
  if (t == 0) scale_s = 1.0f / fmaxf(sqrtf(red[0]+red[1]+red[2]+red[3]), 1e-12f);
  __syncthreads();
  float sc = scale_s;
  if (t < 192) {
    short4_t b; b[0]=f2bf(v[0]*sc); b[1]=f2bf(v[1]*sc); b[2]=f2bf(v[2]*sc); b[3]=f2bf(v[3]*sc);
    *(short4_t*)(qn + (size_t)p * DEMB + t * 4) = b;
  }
}

// Et[d][key] = Eb[key][d]
__global__ void k_transpose(const short* __restrict__ Eb, short* __restrict__ Et) {
  int lane = threadIdx.x & 63;
  int dg   = threadIdx.x >> 6;
  int key  = blockIdx.x * 64 + lane;
  int d0   = blockIdx.y * 32 + dg * 8;
  short8_t v = *(const short8_t*)(Eb + (size_t)key * DEMB + d0);
#pragma unroll
  for (int q = 0; q < 8; ++q)
    Et[(size_t)(d0 + q) * VPAD + key] = v[q];
}

__global__ void k_zero(float* __restrict__ O, float* __restrict__ lsum) {
  int idx = blockIdx.x * 256 + threadIdx.x;      // float4 index over O
  if (idx < NQ) lsum[idx] = 0.f;
  float4_t z = {0.f, 0.f, 0.f, 0.f};
  ((float4_t*)O)[idx] = z;
}

// ===================== GEMM plumbing (BK=64, gemm1) ========================
// 128x128 tile, BK=64: LDS[row*128B + (byte ^ ((row&7)<<4))] = g[row][byte]
__device__ __forceinline__ int swz(int row, int byte) {
  return (row << 7) + (byte ^ ((row & 7) << 4));
}

__device__ __forceinline__ void stage_g2l(short* L, const short* __restrict__ g,
                                          long grow0, long stride, long col0, int tid) {
  int r7 = tid >> 3;
  int c8 = (tid & 7) << 3;                       // short offset, 16B units
#pragma unroll
  for (int i = 0; i < 4; ++i) {
    int  row = r7 + i * 32;
    long cs  = (long)(c8 ^ ((row & 7) << 3));    // pre-swizzled source col (shorts)
    const short* src = g + (grow0 + row) * stride + col0 + cs;
    short* dst = L + row * 64 + c8;              // linear: lane-monotone 16B/lane
    __builtin_amdgcn_global_load_lds(
        (const __attribute__((address_space(1))) void*)src,
        (__attribute__((address_space(3))) void*)dst, 16, 0, 0);
  }
}

__device__ __forceinline__ short8_t ldfrag(const short* L, int row, int kbyte) {
  return *(const short8_t*)(L + (swz(row, kbyte) >> 1));
}

// ===================== GEMM plumbing (BK=32, gemm2) ========================
// 128x32 tiles, 64B rows. Swizzle f(row) = ((row>>1)&3)<<4 (bytes): combined
// with the row-parity bank offset this spreads a 16-row column read over all
// 32 banks at 2-way aliasing (free). Same involution on source and read.
__device__ __forceinline__ void stage32(short* L, const short* __restrict__ g,
                                        long grow0, long stride, long col0, int tid) {
  int c8 = (tid & 3) << 3;                       // 16B slot within 64B row
#pragma unroll
  for (int i = 0; i < 2; ++i) {
    int  row = (tid >> 2) + i * 64;
    long cs  = (long)(c8 ^ (((row >> 1) & 3) << 3));  // pre-swizzled source (shorts)
    const short* src = g + (grow0 + row) * stride + col0 + cs;
    short* dst = L + row * 32 + c8;              // linear LDS dest
    __builtin_amdgcn_global_load_lds(
        (const __attribute__((address_space(1))) void*)src,
        (__attribute__((address_space(3))) void*)dst, 16, 0, 0);
  }
}

__device__ __forceinline__ short8_t ldfrag32(const short* L, int row, int kbyte) {
  int b = (row << 6) + (kbyte ^ (((row >> 1) & 3) << 4));
  return *(const short8_t*)(L + (b >> 1));
}

// ---- GEMM1 (pure): S[p][jc] = qn_p . Eb_j   (raw sim, f16) ----
__global__ __launch_bounds__(256) void k_gemm1(
    const short* __restrict__ qn, const short* __restrict__ Eb,
    _Float16* __restrict__ S, int c0, int KC) {
  __shared__ short lA[128 * 64];
  __shared__ short lB[128 * 64];
  int tid = threadIdx.x, lane = tid & 63;
  int wv = tid >> 6, wr = wv >> 1, wc = wv & 1;
  int rowbase = blockIdx.x * 128;
  int colbase = blockIdx.y * 128;
  float4_t acc[4][4];
  float4_t zero = {0.f, 0.f, 0.f, 0.f};
#pragma unroll
  for (int mt = 0; mt < 4; ++mt)
#pragma unroll
    for (int nt = 0; nt < 4; ++nt) acc[mt][nt] = zero;

  for (int kt = 0; kt < DEMB / 64; ++kt) {
    __syncthreads();
    stage_g2l(lA, qn, rowbase,      DEMB, kt * 64, tid);
    stage_g2l(lB, Eb, c0 + colbase, DEMB, kt * 64, tid);
    __syncthreads();
#pragma unroll
    for (int ks = 0; ks < 2; ++ks) {
      int kb = ks * 64 + (lane >> 4) * 16;
      short8_t a[4], b[4];
#pragma unroll
      for (int mt = 0; mt < 4; ++mt) a[mt] = ldfrag(lA, wr * 64 + mt * 16 + (lane & 15), kb);
#pragma unroll
      for (int nt = 0; nt < 4; ++nt) b[nt] = ldfrag(lB, wc * 64 + nt * 16 + (lane & 15), kb);
#pragma unroll
      for (int mt = 0; mt < 4; ++mt)
#pragma unroll
        for (int nt = 0; nt < 4; ++nt)
          acc[mt][nt] = __builtin_amdgcn_mfma_f32_16x16x32_bf16(a[mt], b[nt], acc[mt][nt], 0, 0, 0);
    }
  }
  // epilogue: raw sims -> f16 (C/D layout: col = lane&15, row = (lane>>4)*4 + reg)
#pragma unroll
  for (int mt = 0; mt < 4; ++mt) {
    int prow = rowbase + wr * 64 + mt * 16 + ((lane >> 4) << 2);
    int jc0  = colbase + wc * 64 + (lane & 15);
#pragma unroll
    for (int r = 0; r < 4; ++r) {
      _Float16* dst = S + (size_t)(prow + r) * KC + jc0;
#pragma unroll
      for (int nt = 0; nt < 4; ++nt) dst[nt * 16] = (_Float16)acc[mt][nt][r];
    }
  }
}

// ---- gumbel/softmax pass: in-place f16 sim -> bf16 P, + row-sum atomics ----
// P = exp2(sim*rk2[j] + C16) * rcp(-ln u_j).  8 contiguous cols per thread.
__global__ __launch_bounds__(256) void k_gumbel(
    uint32_t* __restrict__ SP, const float* __restrict__ rk2,
    float* __restrict__ lsum, int c0, int KCeff, int KC) {
  int p    = blockIdx.x;
  int colq = blockIdx.y * 2048 + threadIdx.x * 8;
  float partial = 0.f;
  if (colq < KCeff) {
    uint32_t* base = SP + ((size_t)p * KC + colq) / 2;     // 2B elems -> u32 pairs
    uint4_t sv = *(const uint4_t*)base;                    // 8 f16 sims
    int j0 = c0 + colq;                                    // global vocab col
    float4_t rk_lo = *(const float4_t*)(rk2 + j0);
    float4_t rk_hi = *(const float4_t*)(rk2 + j0 + 4);
    uint32_t bits[8];
    tf8((uint32_t)p * (uint32_t)VOC + (uint32_t)j0, bits);
    float pe[8];
#pragma unroll
    for (int i = 0; i < 8; ++i) {
      uint32_t h = (sv[i >> 1] >> ((i & 1) * 16)) & 0xFFFFu;
      _Float16 hf = *(_Float16*)&h;
      float simf = (float)hf;
      float rkj = (i < 4) ? rk_lo[i] : rk_hi[i - 4];
      float t = neg_ln_u(bits[i]);
      float v = __builtin_amdgcn_exp2f(fmaf(simf, rkj, C16)) * __builtin_amdgcn_rcpf(t);
      bool ok = (j0 + i) < VOC;
      pe[i] = ok ? v : 0.f;
      partial += pe[i];
    }
    uint4_t pkv;
#pragma unroll
    for (int i = 0; i < 4; ++i) {
      uint32_t r;
      asm("v_cvt_pk_bf16_f32 %0, %1, %2" : "=v"(r) : "v"(pe[2 * i]), "v"(pe[2 * i + 1]));
      pkv[i] = r;
    }
    *(uint4_t*)base = pkv;
  }
  for (int off = 32; off; off >>= 1) partial += __shfl_xor(partial, off);
  if ((threadIdx.x & 63) == 0 && partial != 0.f) unsafeAtomicAdd(&lsum[p], partial);
}

// ---- GEMM2: O[p][d] += sum_k P[p][k] * Et[d][k] ----
// 3-deep counted-vmcnt pipeline (T3/T4): BK=32, 3 LDS buffers (48 KB -> 3
// blocks/CU). Per iter: wait ONLY the consumed tile (vmcnt(4): next tile's 4
// loads stay in flight across the barrier), raw s_barrier, issue tile i+2,
// compute tile i. Loads get ~2 compute phases + TLP of flight time.
// Race-safety: barrier(i) closes compute(i-1); issue(i+2) overwrites
// buf[(i-1)%3], which no wave touches after barrier(i).
__global__ __launch_bounds__(256) void k_gemm2(
    const short* __restrict__ P, const short* __restrict__ Et,
    float* __restrict__ O, int c0, int KC, int kseg) {
  __shared__ __align__(16) short lA[3][128 * 32];
  __shared__ __align__(16) short lB[3][128 * 32];
  int tid = threadIdx.x, lane = tid & 63;
  int wv = tid >> 6, wr = wv >> 1, wc = wv & 1;
  int rowbase = blockIdx.x * 128;
  int colbase = blockIdx.y * 128;                // output dim (<768)
  int kbase   = blockIdx.z * kseg;               // within chunk
  float4_t acc[4][4];
  float4_t zero = {0.f, 0.f, 0.f, 0.f};
#pragma unroll
  for (int mt = 0; mt < 4; ++mt)
#pragma unroll
    for (int nt = 0; nt < 4; ++nt) acc[mt][nt] = zero;

  int n = kseg / 32;
  stage32(lA[0], P,  rowbase, KC,   kbase, tid);
  stage32(lB[0], Et, colbase, VPAD, (long)c0 + kbase, tid);
  if (n > 1) {
    stage32(lA[1], P,  rowbase, KC,   kbase + 32, tid);
    stage32(lB[1], Et, colbase, VPAD, (long)c0 + kbase + 32, tid);
  }

  for (int i = 0; i < n; ++i) {
    if (i + 1 < n) { VMW(4); } else { VMW(0); }  // drain ONLY tile i
    __builtin_amdgcn_s_barrier();
    int nxt = i + 2;
    if (nxt < n) {
      int bn = nxt % 3;
      stage32(lA[bn], P,  rowbase, KC,   kbase + nxt * 32, tid);
      stage32(lB[bn], Et, colbase, VPAD, (long)c0 + kbase + nxt * 32, tid);
    }
    int cur = i % 3;
    int kb = (lane >> 4) * 16;
    short8_t a[4], b[4];
#pragma unroll
    for (int mt = 0; mt < 4; ++mt) a[mt] = ldfrag32(lA[cur], wr * 64 + mt * 16 + (lane & 15), kb);
#pragma unroll
    for (int nt = 0; nt < 4; ++nt) b[nt] = ldfrag32(lB[cur], wc * 64 + nt * 16 + (lane & 15), kb);
#pragma unroll
    for (int mt = 0; mt < 4; ++mt)
#pragma unroll
      for (int nt = 0; nt < 4; ++nt)
        acc[mt][nt] = __builtin_amdgcn_mfma_f32_16x16x32_bf16(a[mt], b[nt], acc[mt][nt], 0, 0, 0);
  }
#pragma unroll
  for (int mt = 0; mt < 4; ++mt)
#pragma unroll
    for (int nt = 0; nt < 4; ++nt) {
      int d = colbase + wc * 64 + nt * 16 + (lane & 15);
#pragma unroll
      for (int r = 0; r < 4; ++r) {
        int p = rowbase + wr * 64 + mt * 16 + ((lane >> 4) << 2) + r;
        unsafeAtomicAdd(&O[(size_t)p * DEMB + d], acc[mt][nt][r]);
      }
    }
}

__global__ void k_finalize(const float* __restrict__ O, const float* __restrict__ lsum,
                           float* __restrict__ out) {
  int idx = blockIdx.x * 256 + threadIdx.x;      // float4 index
  float inv = 1.0f / lsum[idx / 192];            // 192 float4 per row
  float4_t v = ((const float4_t*)O)[idx];
  v[0]*=inv; v[1]*=inv; v[2]*=inv; v[3]*=inv;
  ((float4_t*)out)[idx] = v;
}

// ============================ host launcher ================================
extern "C" void kernel_launch(void* const* d_in, const int* in_sizes, int n_in,
                              void* d_out, int out_size, void* d_ws, size_t ws_size,
                              hipStream_t stream) {
  (void)in_sizes; (void)n_in; (void)out_size;
  const int*   ids = (const int*)d_in[0];
  const float* E   = (const float*)d_in[1];
  float*       out = (float*)d_out;

  char* w = (char*)d_ws;
  short* Eb = (short*)w;      w += (size_t)VPAD * DEMB * 2;   // 77.3 MB
  short* Et = (short*)w;      w += (size_t)DEMB * VPAD * 2;   // 77.3 MB
  short* qn = (short*)w;      w += (size_t)NQ * DEMB * 2;     // 6.3 MB
  float* O  = (float*)w;      w += (size_t)NQ * DEMB * 4;     // 12.6 MB
  float* rk2 = (float*)w;     w += (size_t)VPAD * 4;
  float* lsum = (float*)w;    w += NQ * 4;
  void*  SP = (void*)w;       // f16 sim chunk, overwritten in-place with bf16 P
  size_t fixed = (size_t)(w - (char*)d_ws);

  int KC = 2048;
  if      (fixed + (size_t)NQ * 8192 * 2 <= ws_size) KC = 8192;
  else if (fixed + (size_t)NQ * 4096 * 2 <= ws_size) KC = 4096;
  int chunks = (VPAD + KC - 1) / KC;

  k_zero<<<(NQ * DEMB / 4) / 256, 256, 0, stream>>>(O, lsum);
  k_prep_e<<<VPAD, 256, 0, stream>>>(E, Eb, rk2);
  k_prep_q<<<NQ, 256, 0, stream>>>(ids, E, qn);
  k_transpose<<<dim3(VPAD / 64, DEMB / 32), 256, 0, stream>>>(Eb, Et);

  for (int c = 0; c < chunks; ++c) {
    int c0 = c * KC;
    int KCeff = VPAD - c0; if (KCeff > KC) KCeff = KC;        // multiple of 128
    k_gemm1<<<dim3(NQ / 128, KCeff / 128), 256, 0, stream>>>(qn, Eb, (_Float16*)SP, c0, KC);
    k_gumbel<<<dim3(NQ, (KCeff + 2047) / 2048), 256, 0, stream>>>(
        (uint32_t*)SP, rk2, lsum, c0, KCeff, KC);
    int KS = 4;
    while (KS > 1 && (KCeff % (KS * 32)) != 0) KS >>= 1;
    k_gemm2<<<dim3(NQ / 128, DEMB / 128, KS), 256, 0, stream>>>(
        (const short*)SP, Et, O, c0, KC, KCeff / KS);
  }
  k_finalize<<<(NQ * DEMB / 4) / 256, 256, 0, stream>>>(O, lsum, out);
}